// Round 16
// baseline (92.655 us; speedup 1.0000x reference)
//
#include <hip/hip_runtime.h>

#define NE  5
#define V   25
#define NT  300
#define NC  12
#define CO  64
#define WOFF 384        // float offset of packed weights in d_ws
#define STOFF 2048      // float offset of ST buffer in d_ws (aligned)

typedef float f4 __attribute__((ext_vector_type(4)));
typedef float f2 __attribute__((ext_vector_type(2)));

// intra-wave LDS ordering: drain this wave's LDS ops + pin compiler ordering.
#define WSYNC() do { asm volatile("s_waitcnt lgkmcnt(0)" ::: "memory"); \
                     __builtin_amdgcn_sched_barrier(0); } while (0)

__device__ __forceinline__ float hsel(unsigned m, int e, float w) {
    int s = ((int)(m << (31 - e))) >> 31;
    return __int_as_float(__float_as_int(w) & s);
}

// single-t per-wave scratch offsets (floats). Max index 1074 < SCRF 1088.
#define ODV  0      // DV[5][25]    = 125
#define OFP  125    // FP[15][25]   = 375
#define OE_  500    // edge W[5][25]= 125  (dead after P2)
#define OFT  625    // feat [3][25] = 75   (dead after P1)
#define OB_  700    // B[3][5][25]  = 375  (dead after P2)
#define OST  500    // ST[25][16] = 400 overlays OE/OFT (dead) after P2
#define SCRF 1088   // floats per wave (4352B)

// ---- setup: masks + de + padded weights [o][16] (k0..14, bias) ----
__global__ void setup_kernel(const float* __restrict__ h0, const float* __restrict__ h1,
                             const float* __restrict__ h2, const float* __restrict__ h3,
                             const float* __restrict__ h4,
                             const float* __restrict__ wmlp, const float* __restrict__ bmlp,
                             unsigned* __restrict__ ws) {
    int tid = threadIdx.x;
    float* wsf = (float*)ws;
    if (tid < 125) {
        int i = tid / 25, v = tid % 25;
        const float* hp = (i==0)?h0:(i==1)?h1:(i==2)?h2:(i==3)?h3:h4;
        unsigned m = 0;
        for (int e = 0; e < V; ++e) if (hp[v*V + e] != 0.f) m |= (1u << e);
        ws[tid] = m;
    } else if (tid < 250) {
        int idx = tid - 125, i = idx / 25, e = idx % 25;
        const float* hp = (i==0)?h0:(i==1)?h1:(i==2)?h2:(i==3)?h3:h4;
        unsigned m = 0; float s = 0.f;
        for (int u = 0; u < V; ++u) {
            float hv = hp[u*V + e];
            s += hv;
            if (hv != 0.f) m |= (1u << u);
        }
        ws[tid] = m;
        wsf[125 + tid] = (s != 0.f) ? __fdiv_rn(1.f, s) : 0.f;   // DE at [250+idx]
    }
    for (int q = tid; q < CO*16; q += 384) {
        int o = q >> 4, k = q & 15;
        wsf[WOFF + q] = (k < 15) ? wmlp[o*15 + k] : bmlp[o];
    }
}

// ---- kernel A: aggregation, one wave per t; ST -> d_ws ----
__global__ __launch_bounds__(256, 8) void hyper_agg(
    const float* __restrict__ x,
    const unsigned* __restrict__ ws,
    float* __restrict__ wsf_out)
{
    __shared__ unsigned RM[125];
    __shared__ unsigned CM[125];
    __shared__ float    DE[125];
    __shared__ __align__(16) float SCR[4][SCRF];

    const int tid  = threadIdx.x;
    const int lane = tid & 63;
    const int wid  = tid >> 6;
    const int b    = blockIdx.y;
    const float* wsf = (const float*)ws;

    if (tid < 125) {
        RM[tid] = ws[tid];
    } else if (tid < 250) {
        CM[tid - 125] = ws[tid];
        DE[tid - 125] = wsf[tid + 125];
    }
    __syncthreads();   // only block-wide barrier

    const int t = blockIdx.x * 4 + wid;   // 75*4 = 300 exact
    float* S = SCR[wid];

    // ---- prologue: 8 channels x 25 = 200 items, 4 rounds ----
    #pragma unroll
    for (int r = 0; r < 4; ++r) {
        int q = r*64 + lane;
        if (q < 200) {
            int ch = q / 25, e = q % 25;
            int xc = (ch < 5) ? (ch + 6 + (ch >= 2 ? 1 : 0)) : (ch - 5);
            int o = (ch < 5) ? (OE_ + ch*25 + e) : (OFT + (ch-5)*25 + e);
            S[o] = x[((size_t)(b*NC + xc)*NT + t)*V + e];
        }
    }
    WSYNC();

    // ---- P1: dv via mod-4 class bit-loops (bit-exact numpy association) + B ----
    #pragma unroll
    for (int r = 0; r < 2; ++r) {
        int idx = r*64 + lane;
        if (idx < 125) {
            int i = idx / 25, v = idx % 25;
            unsigned m = RM[idx];
            const float* wi = S + OE_ + i*25;
            float L0 = 0.f, L1 = 0.f, L2 = 0.f, L3 = 0.f;
            unsigned mm;
            mm = m & 0x00111111u;
            while (mm) { int e = __builtin_ctz(mm); mm &= mm-1; L0 = __fadd_rn(L0, wi[e]); }
            mm = m & 0x00222222u;
            while (mm) { int e = __builtin_ctz(mm); mm &= mm-1; L1 = __fadd_rn(L1, wi[e]); }
            mm = m & 0x00444444u;
            while (mm) { int e = __builtin_ctz(mm); mm &= mm-1; L2 = __fadd_rn(L2, wi[e]); }
            mm = m & 0x00888888u;
            while (mm) { int e = __builtin_ctz(mm); mm &= mm-1; L3 = __fadd_rn(L3, wi[e]); }
            float s = __fadd_rn(__fadd_rn(L0, L1), __fadd_rn(L2, L3));
            s = __fadd_rn(s, hsel(m, 24, wi[24]));
            float dvv = (s > 0.f) ? (float)(1.0 / sqrt((double)s)) : 0.f;
            S[ODV + i*25 + v] = dvv;
            S[OB_ +   0 + i*25 + v] = dvv * S[OFT +  0 + v];
            S[OB_ + 125 + i*25 + v] = dvv * S[OFT + 25 + v];
            S[OB_ + 250 + i*25 + v] = dvv * S[OFT + 50 + v];
        }
    }
    WSYNC();

    // ---- P2: FP[3i+c][e] = (w[e]*de[e]) * sum_u h[u,e]*B[c][i][u] ----
    #pragma unroll
    for (int r = 0; r < 2; ++r) {
        int idx = r*64 + lane;
        if (idx < 125) {
            int i = idx / 25, e = idx % 25;
            unsigned m = CM[idx];
            const float* bp = S + OB_ + i*25;
            float a0 = 0.f, a1 = 0.f, a2 = 0.f;
            while (m) {
                int u = __builtin_ctz(m); m &= m - 1;
                a0 += bp[u]; a1 += bp[125 + u]; a2 += bp[250 + u];
            }
            float gg = S[OE_ + i*25 + e] * DE[idx];
            S[OFP + (i*3+0)*25 + e] = a0 * gg;
            S[OFP + (i*3+1)*25 + e] = a1 * gg;
            S[OFP + (i*3+2)*25 + e] = a2 * gg;
        }
    }
    WSYNC();

    // ---- P3: ST[v][3i+c] = dv * sum_e h[v,e]*FP[3i+c][e]; zero k=15 ----
    #pragma unroll
    for (int r = 0; r < 3; ++r) {
        int idx = r*64 + lane;
        if (idx < 125) {
            int i = idx / 25, v = idx % 25;
            unsigned m = RM[idx];
            const float* fp = S + OFP + i*3*25;
            float a0 = 0.f, a1 = 0.f, a2 = 0.f;
            while (m) {
                int e = __builtin_ctz(m); m &= m - 1;
                a0 += fp[e]; a1 += fp[25 + e]; a2 += fp[50 + e];
            }
            float dd = S[ODV + i*25 + v];
            float* st = S + OST + v*16 + i*3;
            st[0] = a0 * dd; st[1] = a1 * dd; st[2] = a2 * dd;
        } else if (idx < 150) {
            S[OST + (idx - 125)*16 + 15] = 0.f;
        }
    }
    WSYNC();

    // ---- P4': ST rows -> global (64B/lane, lanes 0..24 contiguous) ----
    if (lane < 25) {
        const f4* sr = (const f4*)(S + OST + lane*16);
        f4 r0 = sr[0], r1 = sr[1], r2 = sr[2], r3 = sr[3];
        f4* stg = (f4*)(wsf_out + STOFF) + ((size_t)b*7500 + t*25 + lane)*4;
        __builtin_nontemporal_store(r0, stg + 0);
        __builtin_nontemporal_store(r1, stg + 1);
        __builtin_nontemporal_store(r2, stg + 2);
        __builtin_nontemporal_store(r3, stg + 3);
    }
}

// ---- kernel B: streaming MLP; thread = one p position, 64 outputs ----
__global__ __launch_bounds__(256, 8) void hyper_mlp(
    const unsigned* __restrict__ ws,
    float* __restrict__ out)
{
    const float* wsf = (const float*)ws;
    const int p = blockIdx.x * 256 + threadIdx.x;
    if (p >= 7500) return;
    const int b = blockIdx.y;

    const f4* sp = (const f4*)(wsf + STOFF) + ((size_t)b*7500 + p)*4;
    f4 s0 = sp[0], s1 = sp[1], s2 = sp[2], s3 = sp[3];

    float* ob = out + (size_t)b*CO*7500 + p;
    const f4* wq = (const f4*)(wsf + WOFF);
    #pragma unroll 4
    for (int o = 0; o < CO; ++o) {
        f4 c0 = wq[4*o+0], c1 = wq[4*o+1], c2 = wq[4*o+2], c3 = wq[4*o+3];
        f2 acc = (f2){c3.w, 0.f};                      // bias
        acc += (f2){c0.x, c0.y} * (f2){s0.x, s0.y};    // k0,k1
        acc += (f2){c0.z, c0.w} * (f2){s0.z, s0.w};    // k2,k3
        acc += (f2){c1.x, c1.y} * (f2){s1.x, s1.y};    // k4,k5
        acc += (f2){c1.z, c1.w} * (f2){s1.z, s1.w};    // k6,k7
        acc += (f2){c2.x, c2.y} * (f2){s2.x, s2.y};    // k8,k9
        acc += (f2){c2.z, c2.w} * (f2){s2.z, s2.w};    // k10,k11
        acc += (f2){c3.x, c3.y} * (f2){s3.x, s3.y};    // k12,k13
        float res = acc.x + __fmaf_rn(c3.z, s3.z, acc.y);   // k14 + fold
        __builtin_nontemporal_store(fmaxf(res, 0.f), ob + (size_t)o*7500);
    }
}

extern "C" void kernel_launch(void* const* d_in, const int* in_sizes, int n_in,
                              void* d_out, int out_size, void* d_ws, size_t ws_size,
                              hipStream_t stream) {
    const float* x    = (const float*)d_in[0];
    const float* h0   = (const float*)d_in[1];
    const float* h1   = (const float*)d_in[2];
    const float* h2   = (const float*)d_in[3];
    const float* h3   = (const float*)d_in[4];
    const float* h4   = (const float*)d_in[5];
    const float* wmlp = (const float*)d_in[6];
    const float* bmlp = (const float*)d_in[7];
    float* out = (float*)d_out;
    unsigned* wsm = (unsigned*)d_ws;

    setup_kernel<<<dim3(1,1,1), dim3(384,1,1), 0, stream>>>(
        h0, h1, h2, h3, h4, wmlp, bmlp, wsm);
    hyper_agg<<<dim3(75, 64, 1), dim3(256,1,1), 0, stream>>>(
        x, wsm, (float*)d_ws);
    hyper_mlp<<<dim3(30, 64, 1), dim3(256,1,1), 0, stream>>>(
        wsm, out);
}

// Round 17
// 73.492 us; speedup vs baseline: 1.2607x; 1.2607x over previous
//
#include <hip/hip_runtime.h>

#define NE  5
#define V   25
#define NT  300
#define NC  12
#define CO  64
#define WPB 4
#define GX  38          // 38*4 = 152 wave-tasks; 150 t-pairs (2 idle)

typedef float f4 __attribute__((ext_vector_type(4)));

// intra-wave LDS ordering: drain this wave's LDS ops + pin compiler ordering.
#define WSYNC() do { asm volatile("s_waitcnt lgkmcnt(0)" ::: "memory"); \
                     __builtin_amdgcn_sched_barrier(0); } while (0)

// select w if bit e of m set, else +0.0 (sum-equivalent to h*w, h in {0,1})
__device__ __forceinline__ float hsel(unsigned m, int e, float w) {
    int s = ((int)(m << (31 - e))) >> 31;
    return __int_as_float(__float_as_int(w) & s);
}

// per-wave scratch float offsets (rows 28 floats = 112B; OST rows 20 floats)
// max index = OST + 50*20 = 2344 == SCRF (exact fit, verified in R10)
#define OW   0      // W[8][28]   rows 0-4 edge w, rows 5-7 feat
#define ODV  224    // DV[5][28]
#define OG   364    // G[5][28]
#define OB   504    // B[3][5][28]   (c,i,u)
#define OFP  924    // FP[15][28]    (k=3i+c, e)
#define OST  1344   // ST[50][20]    row = tp*25+v
#define SCRF 2344   // floats per wave

__global__ __launch_bounds__(256, 4) void hyper_main(
    const float* __restrict__ x,
    const float* __restrict__ h0, const float* __restrict__ h1,
    const float* __restrict__ h2, const float* __restrict__ h3,
    const float* __restrict__ h4,
    const float* __restrict__ wmlp, const float* __restrict__ bmlp,
    float* __restrict__ out)
{
    __shared__ unsigned RM[125];   // row masks [i*25+v] over e
    __shared__ unsigned CM[125];   // col masks [i*25+e] over u
    __shared__ float    DE[125];   // 1/degree_e
    __shared__ __align__(16) float SCR[WPB][SCRF];

    const int tid  = threadIdx.x;
    const int lane = tid & 63;
    const int wid  = tid >> 6;
    const int b    = blockIdx.y;

    // ---- block init (all branches within 256 threads) ----
    if (tid < 125) {
        int i = tid / 25, v = tid % 25;
        const float* hp = (i==0)?h0:(i==1)?h1:(i==2)?h2:(i==3)?h3:h4;
        unsigned m = 0;
        for (int e = 0; e < V; ++e) if (hp[v*V + e] != 0.f) m |= (1u << e);
        RM[tid] = m;
    } else if (tid < 250) {
        int idx = tid - 125, i = idx / 25, e = idx % 25;
        const float* hp = (i==0)?h0:(i==1)?h1:(i==2)?h2:(i==3)?h3:h4;
        unsigned m = 0; float s = 0.f;
        for (int u = 0; u < V; ++u) {
            float hv = hp[u*V + e];
            s += hv;
            if (hv != 0.f) m |= (1u << u);
        }
        CM[idx] = m;
        DE[idx] = (s != 0.f) ? __fdiv_rn(1.f, s) : 0.f;
    }
    __syncthreads();   // only block-wide barrier

    const int pp = blockIdx.x * WPB + wid;   // one t-pair per wave
    if (pp >= NT/2) return;

    float* S = SCR[wid];

    // ---- prefetch lane constants: item q = r*64+lane over 200 = 8ch x 25e ----
    const float* xb[4]; int lo[4];
    {
        #pragma unroll
        for (int r = 0; r < 4; ++r) {
            int q  = r*64 + lane;
            int qq = (q < 200) ? q : 0;
            int ch = qq / 25, e = qq % 25;
            int xc = (ch < 5) ? (ch + 6 + (ch >= 2 ? 1 : 0)) : (ch - 5);
            lo[r] = OW + ch*28 + e;
            xb[r] = x + (size_t)(b*NC + xc)*NT*V + e;
        }
    }
    const bool act3 = (lane < 8);      // r=3 valid items: q=192..199

    // prologue prefetch: t = 2*pp
    float pf0, pf1, pf2, pf3;
    {
        int t0 = 2 * pp;
        pf0 = xb[0][t0*V]; pf1 = xb[1][t0*V];
        pf2 = xb[2][t0*V]; pf3 = xb[3][t0*V];
    }

    for (int tp = 0; tp < 2; ++tp) {

        // ---- commit prefetched W (prev t's W-reads drained by prior WSYNC) ----
        S[lo[0]] = pf0; S[lo[1]] = pf1; S[lo[2]] = pf2;
        if (act3) S[lo[3]] = pf3;
        WSYNC();

        // ---- issue next-t prefetch (hidden under P1-P3 compute) ----
        if (tp == 0) {
            int tn = 2*pp + 1;
            pf0 = xb[0][tn*V]; pf1 = xb[1][tn*V];
            pf2 = xb[2][tn*V]; pf3 = xb[3][tn*V];
        }

        // ---- P1: dv (bit-exact numpy fp32 association) + g + B fused ----
        for (int r = 0; r < 2; ++r) {
            int idx = r*64 + lane;
            if (idx < 125) {
                int i = idx / 25, v = idx % 25;
                unsigned m = RM[idx];
                const float* wi = S + OW + i*28;
                f4 w0 = *(const f4*)(wi+0),  w1 = *(const f4*)(wi+4),
                   w2 = *(const f4*)(wi+8),  w3 = *(const f4*)(wi+12),
                   w4 = *(const f4*)(wi+16), w5 = *(const f4*)(wi+20),
                   w6 = *(const f4*)(wi+24);
                float L0 = 0.f, L1 = 0.f, L2 = 0.f, L3 = 0.f;
                L0=__fadd_rn(L0,hsel(m, 0,w0.x)); L1=__fadd_rn(L1,hsel(m, 1,w0.y));
                L2=__fadd_rn(L2,hsel(m, 2,w0.z)); L3=__fadd_rn(L3,hsel(m, 3,w0.w));
                L0=__fadd_rn(L0,hsel(m, 4,w1.x)); L1=__fadd_rn(L1,hsel(m, 5,w1.y));
                L2=__fadd_rn(L2,hsel(m, 6,w1.z)); L3=__fadd_rn(L3,hsel(m, 7,w1.w));
                L0=__fadd_rn(L0,hsel(m, 8,w2.x)); L1=__fadd_rn(L1,hsel(m, 9,w2.y));
                L2=__fadd_rn(L2,hsel(m,10,w2.z)); L3=__fadd_rn(L3,hsel(m,11,w2.w));
                L0=__fadd_rn(L0,hsel(m,12,w3.x)); L1=__fadd_rn(L1,hsel(m,13,w3.y));
                L2=__fadd_rn(L2,hsel(m,14,w3.z)); L3=__fadd_rn(L3,hsel(m,15,w3.w));
                L0=__fadd_rn(L0,hsel(m,16,w4.x)); L1=__fadd_rn(L1,hsel(m,17,w4.y));
                L2=__fadd_rn(L2,hsel(m,18,w4.z)); L3=__fadd_rn(L3,hsel(m,19,w4.w));
                L0=__fadd_rn(L0,hsel(m,20,w5.x)); L1=__fadd_rn(L1,hsel(m,21,w5.y));
                L2=__fadd_rn(L2,hsel(m,22,w5.z)); L3=__fadd_rn(L3,hsel(m,23,w5.w));
                float s = __fadd_rn(__fadd_rn(L0,L1), __fadd_rn(L2,L3));
                s = __fadd_rn(s, hsel(m, 24, w6.x));
                float dvv = (s > 0.f) ? (float)(1.0 / sqrt((double)s)) : 0.f;
                S[ODV + i*28 + v] = dvv;
                S[OG  + i*28 + v] = S[OW + i*28 + v] * DE[idx];
                float f0 = S[OW + 5*28 + v];
                float f1 = S[OW + 6*28 + v];
                float f2v = S[OW + 7*28 + v];
                S[OB + (0*5+i)*28 + v] = dvv * f0;
                S[OB + (1*5+i)*28 + v] = dvv * f1;
                S[OB + (2*5+i)*28 + v] = dvv * f2v;
            }
        }
        WSYNC();

        // ---- P2: FP[3i+c][e] = g[i][e]*sum_u h[u,e]*B[c][i][u] ----
        for (int r = 0; r < 2; ++r) {
            int idx = r*64 + lane;
            if (idx < 125) {
                int i = idx / 25, e = idx % 25;
                unsigned m = CM[idx];
                const float* bp = S + OB + i*28;
                float a0 = 0.f, a1 = 0.f, a2 = 0.f;
                while (m) {
                    int u = __builtin_ctz(m); m &= m - 1;
                    a0 += bp[u]; a1 += bp[140 + u]; a2 += bp[280 + u];
                }
                float gg = S[OG + i*28 + e];
                S[OFP + (i*3+0)*28 + e] = a0 * gg;
                S[OFP + (i*3+1)*28 + e] = a1 * gg;
                S[OFP + (i*3+2)*28 + e] = a2 * gg;
            }
        }
        WSYNC();

        // ---- P3: ST[tp*25+v][3i+c] = dv * sum_e h[v,e]*FP[3i+c][e] ----
        for (int r = 0; r < 2; ++r) {
            int idx = r*64 + lane;
            if (idx < 125) {
                int i = idx / 25, v = idx % 25;
                unsigned m = RM[idx];
                const float* fp = S + OFP + i*3*28;
                float a0 = 0.f, a1 = 0.f, a2 = 0.f;
                while (m) {
                    int e = __builtin_ctz(m); m &= m - 1;
                    a0 += fp[e]; a1 += fp[28 + e]; a2 += fp[56 + e];
                }
                float dd = S[ODV + i*28 + v];
                float* st = S + OST + (tp*25 + v)*20 + i*3;
                st[0] = a0 * dd; st[1] = a1 * dd; st[2] = a2 * dd;
            }
        }
        WSYNC();
    }

    // ---- P4: MLP + relu. PLAIN SCALAR per-o chain: 15 v_fma + fmax + store.
    // No f2 packing (R10's (f2){wa[k],wb[k]} cost ~30 v_mov per o-pair —
    // ~2/3 of P4's VALU). Per-output math order identical to R10 (bias
    // first, k0..k14 ascending) -> bit-identical results. ----
    if (lane < 50) {
        const float* st = S + OST + lane*20;
        f4 s0 = *(const f4*)(st+0), s1 = *(const f4*)(st+4),
           s2 = *(const f4*)(st+8), s3 = *(const f4*)(st+12);
        s3.w = 0.f;
        float* ob = out + (size_t)b*CO*7500 + (size_t)pp*50 + lane;
        #pragma unroll 8
        for (int o = 0; o < CO; ++o) {
            const float* wm = wmlp + o*15;   // wave-uniform -> scalar loads
            float a = bmlp[o];
            a = fmaf(wm[ 0], s0.x, a); a = fmaf(wm[ 1], s0.y, a);
            a = fmaf(wm[ 2], s0.z, a); a = fmaf(wm[ 3], s0.w, a);
            a = fmaf(wm[ 4], s1.x, a); a = fmaf(wm[ 5], s1.y, a);
            a = fmaf(wm[ 6], s1.z, a); a = fmaf(wm[ 7], s1.w, a);
            a = fmaf(wm[ 8], s2.x, a); a = fmaf(wm[ 9], s2.y, a);
            a = fmaf(wm[10], s2.z, a); a = fmaf(wm[11], s2.w, a);
            a = fmaf(wm[12], s3.x, a); a = fmaf(wm[13], s3.y, a);
            a = fmaf(wm[14], s3.z, a);
            __builtin_nontemporal_store(fmaxf(a, 0.f), ob + (size_t)o*7500);
        }
    }
}

extern "C" void kernel_launch(void* const* d_in, const int* in_sizes, int n_in,
                              void* d_out, int out_size, void* d_ws, size_t ws_size,
                              hipStream_t stream) {
    const float* x    = (const float*)d_in[0];
    const float* h0   = (const float*)d_in[1];
    const float* h1   = (const float*)d_in[2];
    const float* h2   = (const float*)d_in[3];
    const float* h3   = (const float*)d_in[4];
    const float* h4   = (const float*)d_in[5];
    const float* wmlp = (const float*)d_in[6];
    const float* bmlp = (const float*)d_in[7];
    float* out = (float*)d_out;

    hyper_main<<<dim3(GX, 64, 1), dim3(256,1,1), 0, stream>>>(
        x, h0, h1, h2, h3, h4, wmlp, bmlp, out);
}